// Round 9
// baseline (50.997 us; speedup 1.0000x reference)
//
#include <hip/hip_runtime.h>
#include <hip/hip_fp16.h>

// term = log(sigmoid(x) + 1e-8) ~= -log(1 + min(exp(-x), 1e8))
// 1e8 clamp implements the +1e-8 floor (-log(1+1e8) = -18.42). Band error
// x in [-20,-16]: <=0.69/term, ~0.3% population -> ~2e3 total << 9.6e4 thr.
// 4-way log pairing: prod (1+t_k) <= 1e32 < fp32 max. 10 trans / 8 terms.
// Math identical to R3/R7/R8 (all passed, absmax 0.0).
//
// R9 experiment: table gathers via global_load_lds (LDS-DMA path, per-lane
// global src -> wave-uniform LDS base + lane*16), software-pipelined with
// counted vmcnt waits. Tests whether the LDS-DMA queue is deeper than the
// ~72-entry per-CU vector-memory outstanding cap that R1-R8 saturated.

typedef unsigned int u32x4 __attribute__((ext_vector_type(4)));

#define TPB   256
#define NBLK  2048
#define TTLL  ((long long)NBLK * TPB)   // total threads = 524288

__device__ __forceinline__ float edge_term(u32x4 A, u32x4 B) {
    float t[8];
#pragma unroll
    for (int k = 0; k < 4; ++k) {
        __half2 a = __builtin_bit_cast(__half2, A[k]);
        __half2 b = __builtin_bit_cast(__half2, B[k]);
        __half2 xh = __hmul2(a, b);      // inf-safe: limits correct
        float2 xf = __half22float2(xh);
        t[2 * k]     = fminf(__expf(-xf.x), 1.0e8f);
        t[2 * k + 1] = fminf(__expf(-xf.y), 1.0e8f);
    }
    float p0 = 1.0f + t[0];
    p0 = __builtin_fmaf(p0, t[1], p0);
    p0 = __builtin_fmaf(p0, t[2], p0);
    p0 = __builtin_fmaf(p0, t[3], p0);
    float p1 = 1.0f + t[4];
    p1 = __builtin_fmaf(p1, t[5], p1);
    p1 = __builtin_fmaf(p1, t[6], p1);
    p1 = __builtin_fmaf(p1, t[7], p1);
    return __logf(p0) + __logf(p1);      // positive; negated at the end
}

// ---------------- K0: c[n][0..7] fp16 packed (16 B/node); last block zeroes out
__global__ void compute_c_h8(const float* __restrict__ mu,
                             const float* __restrict__ ls,
                             const float* __restrict__ eps,
                             __half2* __restrict__ c, int N,
                             float* __restrict__ out, int out_size) {
    if (blockIdx.x == gridDim.x - 1) {
        for (int i = threadIdx.x; i < out_size; i += blockDim.x) out[i] = 0.0f;
        return;
    }
    int n = blockIdx.x * blockDim.x + threadIdx.x;
    if (n >= N) return;
    float m  = mu[n];
    float sg = __expf(ls[n]);
    float v[8];
#pragma unroll
    for (int s = 0; s < 8; ++s) v[s] = m + sg * eps[(size_t)s * N + n];
    __half2* dst = c + (size_t)n * 4;
#pragma unroll
    for (int s = 0; s < 4; ++s) dst[s] = __floats2half2_rn(v[2 * s], v[2 * s + 1]);
}

#define GLOAD_LDS(gp, lp)                                                        \
    __builtin_amdgcn_global_load_lds(                                            \
        (const __attribute__((address_space(1))) void*)(gp),                     \
        (__attribute__((address_space(3))) void*)(lp), 16, 0, 0)

// ---------------- edge kernel: LDS-DMA gathers, software-pipelined.
// Per wave: 2 double-buffered 2KB slots (i-entries at +0, j-entries at +1024).
// Queue discipline (FIFO vmcnt): per iter issue [e_{t+2} load, gathers(e_{t+1})],
// then vmcnt(3) guarantees gathers(e_t) retired before reading buf[t&1].
__global__ void __launch_bounds__(TPB, 8)
edge_loglik_lds(const int2* __restrict__ edges, const u32x4* __restrict__ c,
                float* __restrict__ out, long long E, int NIT, float neg_inv_s) {
    __shared__ char smem[TPB / 64 * 4096];           // 4 waves * 2 bufs * 2KB
    long long tid  = (long long)blockIdx.x * TPB + threadIdx.x;
    int  lane  = threadIdx.x & 63;
    int  wid   = threadIdx.x >> 6;
    char* wb   = smem + wid * 4096;                  // wave-private region
    float acc  = 0.0f;

    // prologue: edge 0
    long long i0 = tid < E ? tid : (E - 1);
    int2 e_cur  = edges[i0];                         // compiler waits before use
    GLOAD_LDS(c + e_cur.x, wb);                      // buf0 i-slot
    GLOAD_LDS(c + e_cur.y, wb + 1024);               // buf0 j-slot
    long long i1 = tid + TTLL;
    int2 e_next = edges[i1 < E ? i1 : (E - 1)];

    for (int t = 0; t + 1 < NIT; ++t) {
        // issue next-next edge load + next gathers (into buf[(t+1)&1])
        long long i2 = tid + (long long)(t + 2) * TTLL;
        int2 e_n2 = edges[i2 < E ? i2 : (E - 1)];
        char* nb = wb + ((t + 1) & 1) * 2048;
        GLOAD_LDS(c + e_next.x, nb);                 // needs e_next: compiler's
        GLOAD_LDS(c + e_next.y, nb + 1024);          // wait retires older g_t too
        // gathers(e_t) are older than the 3 newest pending ops -> vmcnt(3) safe;
        // "memory" clobber keeps the ds_reads below from hoisting above this.
        asm volatile("s_waitcnt vmcnt(3)" ::: "memory");
        char* cb = wb + (t & 1) * 2048;
        u32x4 A = *(const u32x4*)(cb + lane * 16);
        u32x4 B = *(const u32x4*)(cb + 1024 + lane * 16);
        if (tid + (long long)t * TTLL < E) acc += edge_term(A, B);
        e_cur = e_next;
        e_next = e_n2;
    }
    // epilogue: last edge
    asm volatile("s_waitcnt vmcnt(0)" ::: "memory");
    {
        int t = NIT - 1;
        char* cb = wb + (t & 1) * 2048;
        u32x4 A = *(const u32x4*)(cb + lane * 16);
        u32x4 B = *(const u32x4*)(cb + 1024 + lane * 16);
        if (tid + (long long)t * TTLL < E) acc += edge_term(A, B);
    }

    // wave (64-lane) reduction -> one atomic per block
#pragma unroll
    for (int off = 32; off > 0; off >>= 1) acc += __shfl_down(acc, off, 64);
    __shared__ float wsum[4];
    if (lane == 0) wsum[wid] = acc;
    __syncthreads();
    if (threadIdx.x == 0) {
        float s = 0.0f;
        for (int w = 0; w < TPB / 64; ++w) s += wsum[w];
        atomicAdd(out, s * neg_inv_s);
    }
}

// ---------------- fallback: R7-style direct-gather (plain loads)
__global__ void __launch_bounds__(256, 8)
edge_loglik_direct(const int2* __restrict__ el, const u32x4* __restrict__ c,
                   float* __restrict__ out, long long E, float neg_inv_s) {
    long long tid    = (long long)blockIdx.x * blockDim.x + threadIdx.x;
    long long stride = (long long)gridDim.x * blockDim.x;
    float acc = 0.0f;
    for (long long e = tid; e < E; e += stride) {
        int2 ij = el[e];
        acc += edge_term(c[ij.x], c[ij.y]);
    }
#pragma unroll
    for (int off = 32; off > 0; off >>= 1) acc += __shfl_down(acc, off, 64);
    __shared__ float wsum[4];
    int lane = threadIdx.x & 63, wid = threadIdx.x >> 6;
    if (lane == 0) wsum[wid] = acc;
    __syncthreads();
    if (threadIdx.x == 0) {
        float s = 0.0f;
        for (int w = 0; w < (int)(blockDim.x >> 6); ++w) s += wsum[w];
        atomicAdd(out, s * neg_inv_s);
    }
}

// ---------------- generic-S fallback (harness uses S=8; kept for safety)
__global__ void compute_c_gen(const float* __restrict__ mu, const float* __restrict__ ls,
                              const float* __restrict__ eps, __half* __restrict__ c,
                              int N, int S, float* __restrict__ out, int out_size) {
    if (blockIdx.x == gridDim.x - 1) {
        for (int i = threadIdx.x; i < out_size; i += blockDim.x) out[i] = 0.0f;
        return;
    }
    int n = blockIdx.x * blockDim.x + threadIdx.x;
    if (n >= N) return;
    float m = mu[n], sg = __expf(ls[n]);
    for (int s = 0; s < S; ++s) c[(size_t)n * S + s] = __float2half(m + sg * eps[(size_t)s * N + n]);
}
__global__ void edge_loglik_gen(const int* __restrict__ ed, const __half* __restrict__ c,
                                float* __restrict__ out, long long E, int S, float neg_inv_s) {
    long long tid = (long long)blockIdx.x * blockDim.x + threadIdx.x;
    long long stride = (long long)gridDim.x * blockDim.x;
    float acc = 0.0f;
    for (long long e = tid; e < E; e += stride) {
        long long i = ed[2 * e], j = ed[2 * e + 1];
        for (int s = 0; s < S; ++s) {
            float x = __half2float(c[i * S + s]) * __half2float(c[j * S + s]);
            acc += __logf(1.0f + fminf(__expf(-x), 1.0e8f));
        }
    }
#pragma unroll
    for (int off = 32; off > 0; off >>= 1) acc += __shfl_down(acc, off, 64);
    __shared__ float wsum[8];
    int lane = threadIdx.x & 63, wid = threadIdx.x >> 6;
    if (lane == 0) wsum[wid] = acc;
    __syncthreads();
    if (threadIdx.x == 0) {
        float s = 0.0f;
        for (int w = 0; w < (int)(blockDim.x >> 6); ++w) s += wsum[w];
        atomicAdd(out, s * neg_inv_s);
    }
}

extern "C" void kernel_launch(void* const* d_in, const int* in_sizes, int n_in,
                              void* d_out, int out_size, void* d_ws, size_t ws_size,
                              hipStream_t stream) {
    const float* mu  = (const float*)d_in[0];
    const float* ls  = (const float*)d_in[1];
    const float* eps = (const float*)d_in[2];
    const int* edges = (const int*)d_in[3];    // int32 pairs (confirmed R4/R5)

    int       N = in_sizes[0];
    int       S = in_sizes[2] / N;             // 8
    long long E = (long long)in_sizes[3] / 2;  // 3.2M

    __half* c  = (__half*)d_ws;
    float* out = (float*)d_out;
    size_t sz_c = (size_t)N * S * sizeof(__half);
    float neg_inv_s = -1.0f / (float)S;

    int cblocks = (N + 255) / 256 + 1;         // +1 block zeroes d_out
    int NIT = (int)((E + TTLL - 1) / TTLL);    // 7 at E=3.2M

    if (S == 8 && ws_size >= sz_c) {
        compute_c_h8<<<cblocks, 256, 0, stream>>>(mu, ls, eps, (__half2*)c, N, out, out_size);
        if (NIT >= 2) {
            edge_loglik_lds<<<NBLK, TPB, 0, stream>>>((const int2*)edges, (const u32x4*)c,
                                                      out, E, NIT, neg_inv_s);
        } else {
            edge_loglik_direct<<<2048, 256, 0, stream>>>((const int2*)edges, (const u32x4*)c,
                                                         out, E, neg_inv_s);
        }
    } else {
        compute_c_gen<<<cblocks, 256, 0, stream>>>(mu, ls, eps, c, N, S, out, out_size);
        edge_loglik_gen<<<2048, 256, 0, stream>>>(edges, c, out, E, S, neg_inv_s);
    }
}